// Round 1
// baseline (219.280 us; speedup 1.0000x reference)
//
#include <hip/hip_runtime.h>
#include <math.h>

#define NM 1024
#define NS 256
#define NK 1025

struct Q4 { float x, y, z, w; };

__device__ __forceinline__ Q4 qmul(const Q4 a, const Q4 b) {
    Q4 o;
    o.x = a.w*b.x + a.x*b.w + a.y*b.z - a.z*b.y;
    o.y = a.w*b.y - a.x*b.z + a.y*b.w + a.z*b.x;
    o.z = a.w*b.z + a.x*b.y - a.y*b.x + a.z*b.w;
    o.w = a.w*b.w - a.x*b.x - a.y*b.y - a.z*b.z;
    return o;
}

__device__ __forceinline__ void q2m(const Q4 q, float* R) {
    float x = q.x, y = q.y, z = q.z, w = q.w;
    R[0] = 1.f - 2.f*(y*y + z*z); R[1] = 2.f*(x*y - z*w);       R[2] = 2.f*(x*z + y*w);
    R[3] = 2.f*(x*y + z*w);       R[4] = 1.f - 2.f*(x*x + z*z); R[5] = 2.f*(y*z - x*w);
    R[6] = 2.f*(x*z - y*w);       R[7] = 2.f*(y*z + x*w);       R[8] = 1.f - 2.f*(x*x + y*y);
}

// ------------------------------------------------------------------
// Phase 1: one thread per sequence m. Sequential scan over S steps.
// Reduced Jacobian state (rows 9:15 of J stay identity; J[6:9,9:12]==0):
//   P1=J[0:3,9:12] P2=J[0:3,12:15] V1=J[3:6,9:12] V2=J[3:6,12:15] Q2=J[6:9,12:15]
// Recurrences (all RHS use previous values; R is rotation AFTER q update):
//   P1 += d*V1            P2 += d*V2
//   V1 -= d*R             V2 -= d * R @ (S(a-ba) @ Q2)
//   Q2  = Q2 - d*(S(w-bw) @ Q2) - d*I
// ------------------------------------------------------------------
__global__ __launch_bounds__(64) void imu_phase1(
    const float* __restrict__ acc, const float* __restrict__ gyro,
    const float* __restrict__ dt, const float* __restrict__ bias_a,
    const float* __restrict__ bias_w, float* __restrict__ ws)
{
    int m = blockIdx.x * 64 + threadIdx.x;
    if (m >= NM) return;

    const float* ap  = acc    + (size_t)m * NS * 3;
    const float* wp  = gyro   + (size_t)m * NS * 3;
    const float* dtp = dt     + (size_t)m * NS;
    const float* bap = bias_a + (size_t)m * NS * 3;
    const float* bwp = bias_w + (size_t)m * NS * 3;

    Q4 q = {0.f, 0.f, 0.f, 1.f};
    float R[9] = {1.f,0.f,0.f, 0.f,1.f,0.f, 0.f,0.f,1.f};
    float vx = 0.f, vy = 0.f, vz = 0.f;
    float px = 0.f, py = 0.f, pz = 0.f;
    float P1[9] = {0.f}, P2[9] = {0.f}, V1[9] = {0.f}, V2[9] = {0.f}, Q2[9] = {0.f};
    float kf = 0.f;

    float ba0x = bap[0], ba0y = bap[1], ba0z = bap[2];
    float bw0x = bwp[0], bw0y = bwp[1], bw0z = bwp[2];

    for (int s = 0; s < NS; ++s) {
        float d  = dtp[s];
        float ax = ap[s*3+0], ay = ap[s*3+1], az = ap[s*3+2];
        float gx = wp[s*3+0], gy = wp[s*3+1], gz = wp[s*3+2];
        kf += d;

        // a_w = R_old @ a ; p,v updates (order matches reference)
        float aw0 = R[0]*ax + R[1]*ay + R[2]*az;
        float aw1 = R[3]*ax + R[4]*ay + R[5]*az;
        float aw2 = R[6]*ax + R[7]*ay + R[8]*az;
        px += vx*d + 0.5f*aw0*d*d;
        py += vy*d + 0.5f*aw1*d*d;
        pz += vz*d + 0.5f*aw2*d*d;
        vx += aw0*d; vy += aw1*d; vz += aw2*d;

        // q = q * quat_exp(w*d)
        float phx = gx*d, phy = gy*d, phz = gz*d;
        float th2 = phx*phx + phy*phy + phz*phz;
        float theta = sqrtf(th2);
        float half = 0.5f*theta;
        float k;
        if (theta < 1e-6f) k = 0.5f - th2*(1.0f/48.0f);
        else               k = sinf(half)/theta;
        Q4 e = {phx*k, phy*k, phz*k, cosf(half)};
        q = qmul(q, e);
        q2m(q, R);  // R_new (used by Jacobian and next step's a_w)

        float abx = ax - bap[s*3+0], aby = ay - bap[s*3+1], abz = az - bap[s*3+2];
        float wbx = gx - bwp[s*3+0], wby = gy - bwp[s*3+1], wbz = gz - bwp[s*3+2];

        // P updates first (use old V)
        #pragma unroll
        for (int i = 0; i < 9; ++i) { P1[i] += d*V1[i]; P2[i] += d*V2[i]; }

        // SQ = S(a-ba) @ Q2_old ; WQ = S(w-bw) @ Q2_old
        float SQ[9], WQ[9];
        #pragma unroll
        for (int c = 0; c < 3; ++c) {
            float q0 = Q2[c], q1 = Q2[3+c], q2c = Q2[6+c];
            SQ[c]   = -abz*q1 + aby*q2c;
            SQ[3+c] =  abz*q0 - abx*q2c;
            SQ[6+c] = -aby*q0 + abx*q1;
            WQ[c]   = -wbz*q1 + wby*q2c;
            WQ[3+c] =  wbz*q0 - wbx*q2c;
            WQ[6+c] = -wby*q0 + wbx*q1;
        }
        // V2 -= d * R @ SQ
        #pragma unroll
        for (int r = 0; r < 3; ++r) {
            #pragma unroll
            for (int c = 0; c < 3; ++c) {
                V2[r*3+c] -= d*(R[r*3+0]*SQ[c] + R[r*3+1]*SQ[3+c] + R[r*3+2]*SQ[6+c]);
            }
        }
        // V1 -= d*R
        #pragma unroll
        for (int i = 0; i < 9; ++i) V1[i] -= d*R[i];
        // Q2 = Q2 - d*WQ - d*I
        #pragma unroll
        for (int i = 0; i < 9; ++i) Q2[i] -= d*WQ[i];
        Q2[0] -= d; Q2[4] -= d; Q2[8] -= d;
    }

    // epilogue per m
    float alpha[3], beta[3];
    float pv[3] = {px, py, pz};
    float vv[3] = {vx, vy, vz};
    #pragma unroll
    for (int r = 0; r < 3; ++r) {
        alpha[r] = pv[r] + P1[r*3+0]*ba0x + P1[r*3+1]*ba0y + P1[r*3+2]*ba0z
                         + P2[r*3+0]*bw0x + P2[r*3+1]*bw0y + P2[r*3+2]*bw0z;
        beta[r]  = vv[r] + V1[r*3+0]*ba0x + V1[r*3+1]*ba0y + V1[r*3+2]*ba0z
                         + V2[r*3+0]*bw0x + V2[r*3+1]*bw0y + V2[r*3+2]*bw0z;
    }
    float dthx = 0.5f*(Q2[0]*bw0x + Q2[1]*bw0y + Q2[2]*bw0z);
    float dthy = 0.5f*(Q2[3]*bw0x + Q2[4]*bw0y + Q2[5]*bw0z);
    float dthz = 0.5f*(Q2[6]*bw0x + Q2[7]*bw0y + Q2[8]*bw0z);
    Q4 dq = {dthx, dthy, dthz, 1.0f};
    Q4 gamma = qmul(q, dq);

    float* g_gamma = ws;            // NM*4
    float* g_beta  = ws + 4*NM;     // NM*3
    float* g_alpha = ws + 7*NM;     // NM*3
    float* g_kf    = ws + 10*NM;    // NM
    g_gamma[m*4+0] = gamma.x; g_gamma[m*4+1] = gamma.y;
    g_gamma[m*4+2] = gamma.z; g_gamma[m*4+3] = gamma.w;
    g_beta[m*3+0] = beta[0];  g_beta[m*3+1] = beta[1];  g_beta[m*3+2] = beta[2];
    g_alpha[m*3+0] = alpha[0]; g_alpha[m*3+1] = alpha[1]; g_alpha[m*3+2] = alpha[2];
    g_kf[m] = kf;
}

// ------------------------------------------------------------------
// Phase 2: single block of 1024 threads. Quat scan + two float3 scans
// in LDS, then elementwise epilogue over K=1025.
// ------------------------------------------------------------------
__global__ __launch_bounds__(1024) void imu_phase2(
    const float* __restrict__ ws, const float* __restrict__ g,
    const float* __restrict__ init_rot, const float* __restrict__ init_pos,
    const float* __restrict__ init_vel, const float* __restrict__ gt_rot,
    const float* __restrict__ gt_pos, const float* __restrict__ gt_vel,
    float* __restrict__ out)
{
    __shared__ float4 srot[NK];       // 16.4 KB — rot quaternions
    __shared__ float  sbuf[NM][3];    // 12 KB  — scan workspace
    __shared__ float  svel[NK][3];    // 12.3 KB
    __shared__ float  spos[NK][3];    // 12.3 KB

    const int tid = threadIdx.x;

    const float* g_gamma = ws;
    const float* g_beta  = ws + 4*NM;
    const float* g_alpha = ws + 7*NM;
    const float* g_kf    = ws + 10*NM;

    Q4 qinit = {init_rot[0], init_rot[1], init_rot[2], init_rot[3]};

    // --- quaternion inclusive scan of gamma, staged at srot[tid+1] ---
    srot[tid+1] = make_float4(g_gamma[tid*4+0], g_gamma[tid*4+1],
                              g_gamma[tid*4+2], g_gamma[tid*4+3]);
    __syncthreads();
    for (int off = 1; off < NM; off <<= 1) {
        float4 a4, b4 = srot[tid+1];
        bool act = (tid >= off);
        if (act) a4 = srot[tid+1-off];
        __syncthreads();
        if (act) {
            Q4 a = {a4.x, a4.y, a4.z, a4.w}, b = {b4.x, b4.y, b4.z, b4.w};
            Q4 c = qmul(a, b);
            srot[tid+1] = make_float4(c.x, c.y, c.z, c.w);
        }
        __syncthreads();
    }
    // rot[k] = init_rot * prefix(gamma)
    {
        float4 p4 = srot[tid+1];
        __syncthreads();
        Q4 p = {p4.x, p4.y, p4.z, p4.w};
        Q4 r = qmul(qinit, p);
        srot[tid+1] = make_float4(r.x, r.y, r.z, r.w);
        if (tid == 0) srot[0] = make_float4(qinit.x, qinit.y, qinit.z, qinit.w);
    }
    __syncthreads();

    const float gx = g[0], gy = g[1], gz = g[2];

    // per-m data (m = tid)
    float4 r4 = srot[tid];
    Q4 rq = {r4.x, r4.y, r4.z, r4.w};
    float Rw[9]; q2m(rq, Rw);
    float kf = g_kf[tid];
    float bx = g_beta[tid*3+0], by = g_beta[tid*3+1], bz = g_beta[tid*3+2];
    float axm = g_alpha[tid*3+0], aym = g_alpha[tid*3+1], azm = g_alpha[tid*3+2];

    // --- dvel scan -> svel ---
    sbuf[tid][0] = -gx*kf + Rw[0]*bx + Rw[1]*by + Rw[2]*bz;
    sbuf[tid][1] = -gy*kf + Rw[3]*bx + Rw[4]*by + Rw[5]*bz;
    sbuf[tid][2] = -gz*kf + Rw[6]*bx + Rw[7]*by + Rw[8]*bz;
    __syncthreads();
    for (int off = 1; off < NM; off <<= 1) {
        float a0, a1, a2;
        float b0 = sbuf[tid][0], b1 = sbuf[tid][1], b2 = sbuf[tid][2];
        bool act = (tid >= off);
        if (act) { a0 = sbuf[tid-off][0]; a1 = sbuf[tid-off][1]; a2 = sbuf[tid-off][2]; }
        __syncthreads();
        if (act) { sbuf[tid][0] = a0+b0; sbuf[tid][1] = a1+b1; sbuf[tid][2] = a2+b2; }
        __syncthreads();
    }
    if (tid == 0) { svel[0][0] = init_vel[0]; svel[0][1] = init_vel[1]; svel[0][2] = init_vel[2]; }
    svel[tid+1][0] = init_vel[0] + sbuf[tid][0];
    svel[tid+1][1] = init_vel[1] + sbuf[tid][1];
    svel[tid+1][2] = init_vel[2] + sbuf[tid][2];
    __syncthreads();

    // --- dpos scan -> spos ---
    float vmx = svel[tid][0], vmy = svel[tid][1], vmz = svel[tid][2];
    __syncthreads();
    sbuf[tid][0] = vmx*kf - 0.5f*gx*kf*kf + Rw[0]*axm + Rw[1]*aym + Rw[2]*azm;
    sbuf[tid][1] = vmy*kf - 0.5f*gy*kf*kf + Rw[3]*axm + Rw[4]*aym + Rw[5]*azm;
    sbuf[tid][2] = vmz*kf - 0.5f*gz*kf*kf + Rw[6]*axm + Rw[7]*aym + Rw[8]*azm;
    __syncthreads();
    for (int off = 1; off < NM; off <<= 1) {
        float a0, a1, a2;
        float b0 = sbuf[tid][0], b1 = sbuf[tid][1], b2 = sbuf[tid][2];
        bool act = (tid >= off);
        if (act) { a0 = sbuf[tid-off][0]; a1 = sbuf[tid-off][1]; a2 = sbuf[tid-off][2]; }
        __syncthreads();
        if (act) { sbuf[tid][0] = a0+b0; sbuf[tid][1] = a1+b1; sbuf[tid][2] = a2+b2; }
        __syncthreads();
    }
    if (tid == 0) { spos[0][0] = init_pos[0]; spos[0][1] = init_pos[1]; spos[0][2] = init_pos[2]; }
    spos[tid+1][0] = init_pos[0] + sbuf[tid][0];
    spos[tid+1][1] = init_pos[1] + sbuf[tid][1];
    spos[tid+1][2] = init_pos[2] + sbuf[tid][2];
    __syncthreads();

    // --- epilogue over k in [0, NK) ---
    for (int k = tid; k < NK; k += 1024) {
        float4 rr = srot[k];
        Q4 rk = {rr.x, rr.y, rr.z, rr.w};
        Q4 gc = {-gt_rot[k*4+0], -gt_rot[k*4+1], -gt_rot[k*4+2], gt_rot[k*4+3]};
        Q4 e = qmul(gc, rk);
        // quat_log
        float n2 = e.x*e.x + e.y*e.y + e.z*e.z;
        float n = sqrtf(n2);
        float theta = 2.f*atan2f(n, e.w);
        float scale;
        if (n < 1e-6f) {
            float wd = (fabsf(e.w) < 1e-6f) ? 1.f : e.w;
            scale = 2.f/wd;
        } else {
            scale = theta/n;
        }
        out[k*3+0] = e.x*scale;
        out[k*3+1] = e.y*scale;
        out[k*3+2] = e.z*scale;

        float d0 = gt_pos[k*3+0] - spos[k][0];
        float d1 = gt_pos[k*3+1] - spos[k][1];
        float d2 = gt_pos[k*3+2] - spos[k][2];
        out[(NK+k)*3+0] = d0*d0;
        out[(NK+k)*3+1] = d1*d1;
        out[(NK+k)*3+2] = d2*d2;

        float e0 = gt_vel[k*3+0] - svel[k][0];
        float e1 = gt_vel[k*3+1] - svel[k][1];
        float e2 = gt_vel[k*3+2] - svel[k][2];
        out[(2*NK+k)*3+0] = e0*e0;
        out[(2*NK+k)*3+1] = e1*e1;
        out[(2*NK+k)*3+2] = e2*e2;
    }
}

extern "C" void kernel_launch(void* const* d_in, const int* in_sizes, int n_in,
                              void* d_out, int out_size, void* d_ws, size_t ws_size,
                              hipStream_t stream) {
    const float* acc      = (const float*)d_in[0];
    const float* gyro     = (const float*)d_in[1];
    const float* dt       = (const float*)d_in[2];
    const float* bias_a   = (const float*)d_in[3];
    const float* bias_w   = (const float*)d_in[4];
    const float* g        = (const float*)d_in[5];
    const float* init_rot = (const float*)d_in[6];
    const float* init_pos = (const float*)d_in[7];
    const float* init_vel = (const float*)d_in[8];
    const float* gt_rot   = (const float*)d_in[9];
    const float* gt_pos   = (const float*)d_in[10];
    const float* gt_vel   = (const float*)d_in[11];
    float* ws  = (float*)d_ws;
    float* out = (float*)d_out;

    imu_phase1<<<NM/64, 64, 0, stream>>>(acc, gyro, dt, bias_a, bias_w, ws);
    imu_phase2<<<1, 1024, 0, stream>>>(ws, g, init_rot, init_pos, init_vel,
                                       gt_rot, gt_pos, gt_vel, out);
}

// Round 2
// 50.631 us; speedup vs baseline: 4.3310x; 4.3310x over previous
//
#include <hip/hip_runtime.h>
#include <math.h>

#define NM 1024
#define NS 256
#define NK 1025
#define CS 16   // steps per chunk
#define NC 16   // chunks per sequence
#define SEQ_PER_BLK 4

struct Q4 { float x, y, z, w; };

__device__ __forceinline__ Q4 qmul(const Q4 a, const Q4 b) {
    Q4 o;
    o.x = a.w*b.x + a.x*b.w + a.y*b.z - a.z*b.y;
    o.y = a.w*b.y - a.x*b.z + a.y*b.w + a.z*b.x;
    o.z = a.w*b.z + a.x*b.y - a.y*b.x + a.z*b.w;
    o.w = a.w*b.w - a.x*b.x - a.y*b.y - a.z*b.z;
    return o;
}

__device__ __forceinline__ void q2m(const Q4 q, float* R) {
    float x = q.x, y = q.y, z = q.z, w = q.w;
    R[0] = 1.f - 2.f*(y*y + z*z); R[1] = 2.f*(x*y - z*w);       R[2] = 2.f*(x*z + y*w);
    R[3] = 2.f*(x*y + z*w);       R[4] = 1.f - 2.f*(x*x + z*z); R[5] = 2.f*(y*z - x*w);
    R[6] = 2.f*(x*z - y*w);       R[7] = 2.f*(y*z + x*w);       R[8] = 1.f - 2.f*(x*x + y*y);
}

// o = X @ Y (3x3)
__device__ __forceinline__ void m3mul(float* o, const float* X, const float* Y) {
    #pragma unroll
    for (int r = 0; r < 3; ++r)
        #pragma unroll
        for (int c = 0; c < 3; ++c)
            o[r*3+c] = X[r*3+0]*Y[c] + X[r*3+1]*Y[3+c] + X[r*3+2]*Y[6+c];
}

// o = skew(x,y,z) @ M (3x3)
__device__ __forceinline__ void skmul(float* o, float x, float y, float z, const float* M) {
    #pragma unroll
    for (int c = 0; c < 3; ++c) {
        float m0 = M[c], m1 = M[3+c], m2 = M[6+c];
        o[c]   = -z*m1 + y*m2;
        o[3+c] =  z*m0 - x*m2;
        o[6+c] = -y*m0 + x*m1;
    }
}

// ------------------------------------------------------------------
// Phase 1 (chunk-parallel): each thread computes the transfer function
// of CS steps of one sequence. Chunk transfer parameters (83 floats):
//   q_out  = q_in (x) E
//   kf_out = kf_in + T
//   v_out  = v_in + R_in u             (R_in = mat(q_in))
//   p_out  = p_in + v_in T + R_in z
//   Q2_out = A Q2_in + B
//   V1_out = V1_in - R_in M1
//   V2_out = V2_in - R_in (N Q2_in + n)
//   P1_out = P1_in + T V1_in - R_in K1
//   P2_out = P2_in + T V2_in - R_in (K2a Q2_in + k2b)
// One lane per sequence then applies the NC transfers sequentially.
// ------------------------------------------------------------------
__global__ __launch_bounds__(64) void imu_phase1(
    const float* __restrict__ acc, const float* __restrict__ gyro,
    const float* __restrict__ dt, const float* __restrict__ bias_a,
    const float* __restrict__ bias_w, float* __restrict__ ws)
{
    __shared__ float trans[SEQ_PER_BLK][NC][84];

    const int seq = threadIdx.x >> 4;          // 0..3
    const int c   = threadIdx.x & 15;          // chunk 0..15
    const int m   = blockIdx.x * SEQ_PER_BLK + seq;
    const int s0  = c * CS;

    const float* ap  = acc    + (size_t)m * NS * 3 + (size_t)s0 * 3;
    const float* wp  = gyro   + (size_t)m * NS * 3 + (size_t)s0 * 3;
    const float* dtp = dt     + (size_t)m * NS     + s0;
    const float* bap = bias_a + (size_t)m * NS * 3 + (size_t)s0 * 3;
    const float* bwp = bias_w + (size_t)m * NS * 3 + (size_t)s0 * 3;

    // chunk-local accumulators
    Q4 fq = {0.f, 0.f, 0.f, 1.f};
    float G[9]  = {1.f,0.f,0.f, 0.f,1.f,0.f, 0.f,0.f,1.f};
    float T = 0.f;
    float u[3] = {0.f}, z[3] = {0.f};
    float A[9]  = {1.f,0.f,0.f, 0.f,1.f,0.f, 0.f,0.f,1.f};
    float Bm[9] = {0.f};
    float M1[9] = {0.f}, N[9] = {0.f}, nn[9] = {0.f};
    float K1[9] = {0.f}, K2a[9] = {0.f}, k2b[9] = {0.f};

    for (int j = 0; j < CS; ++j) {
        float d  = dtp[j];
        float ax = ap[j*3+0], ay = ap[j*3+1], az = ap[j*3+2];
        float gx = wp[j*3+0], gy = wp[j*3+1], gz = wp[j*3+2];
        float abx = ax - bap[j*3+0], aby = ay - bap[j*3+1], abz = az - bap[j*3+2];
        float wbx = gx - bwp[j*3+0], wby = gy - bwp[j*3+1], wbz = gz - bwp[j*3+2];

        // K accumulators use pre-update M1/N/n
        #pragma unroll
        for (int i = 0; i < 9; ++i) {
            K1[i]  += d*M1[i];
            K2a[i] += d*N[i];
            k2b[i] += d*nn[i];
        }

        // a_w local part uses G_s (pre-update)
        float ga0 = G[0]*ax + G[1]*ay + G[2]*az;
        float ga1 = G[3]*ax + G[4]*ay + G[5]*az;
        float ga2 = G[6]*ax + G[7]*ay + G[8]*az;
        float hd2 = 0.5f*d*d;
        z[0] += d*u[0] + hd2*ga0;
        z[1] += d*u[1] + hd2*ga1;
        z[2] += d*u[2] + hd2*ga2;
        u[0] += d*ga0; u[1] += d*ga1; u[2] += d*ga2;
        T += d;

        // quat update: f = f (x) exp(w*d); G = mat(f)  -> G_{s+1}
        float phx = gx*d, phy = gy*d, phz = gz*d;
        float th2 = phx*phx + phy*phy + phz*phz;
        float theta = sqrtf(th2);
        float half = 0.5f*theta;
        float k;
        if (theta < 1e-6f) k = 0.5f - th2*(1.0f/48.0f);
        else               k = sinf(half)/theta;
        Q4 e = {phx*k, phy*k, phz*k, cosf(half)};
        fq = qmul(fq, e);
        q2m(fq, G);

        // M1 += d*G_{s+1}
        #pragma unroll
        for (int i = 0; i < 9; ++i) M1[i] += d*G[i];

        // N += d*G@(S(ab)@A) ; n += d*G@(S(ab)@B)   (A,B pre-update)
        float SA[9], SB[9], GX[9];
        skmul(SA, abx, aby, abz, A);
        skmul(SB, abx, aby, abz, Bm);
        m3mul(GX, G, SA);
        #pragma unroll
        for (int i = 0; i < 9; ++i) N[i] += d*GX[i];
        m3mul(GX, G, SB);
        #pragma unroll
        for (int i = 0; i < 9; ++i) nn[i] += d*GX[i];

        // A <- (I - d W)A ; B <- (I - d W)B - d I
        float WA[9], WB[9];
        skmul(WA, wbx, wby, wbz, A);
        skmul(WB, wbx, wby, wbz, Bm);
        #pragma unroll
        for (int i = 0; i < 9; ++i) { A[i] -= d*WA[i]; Bm[i] -= d*WB[i]; }
        Bm[0] -= d; Bm[4] -= d; Bm[8] -= d;
    }

    // stage transfer into LDS
    {
        float* t = trans[seq][c];
        t[0] = fq.x; t[1] = fq.y; t[2] = fq.z; t[3] = fq.w;
        t[4] = T;
        t[5] = u[0]; t[6] = u[1]; t[7] = u[2];
        t[8] = z[0]; t[9] = z[1]; t[10] = z[2];
        #pragma unroll
        for (int i = 0; i < 9; ++i) {
            t[11+i] = A[i];  t[20+i] = Bm[i]; t[29+i] = M1[i];
            t[38+i] = N[i];  t[47+i] = nn[i]; t[56+i] = K1[i];
            t[65+i] = K2a[i]; t[74+i] = k2b[i];
        }
    }
    __syncthreads();

    if (c != 0) return;

    // ---- sequential combine over NC chunks ----
    float q[4] = {0.f, 0.f, 0.f, 1.f};
    float v[3] = {0.f}, p[3] = {0.f};
    float Q2[9] = {0.f}, V1[9] = {0.f}, V2[9] = {0.f}, P1[9] = {0.f}, P2[9] = {0.f};
    float kf = 0.f;

    for (int cc = 0; cc < NC; ++cc) {
        const float* t = trans[seq][cc];
        float R[9];
        Q4 qq = {q[0], q[1], q[2], q[3]};
        q2m(qq, R);
        float Tc = t[4];
        float tmp[9], tmp2[9];

        // P1 += T*V1 - R@K1
        m3mul(tmp, R, t+56);
        #pragma unroll
        for (int i = 0; i < 9; ++i) P1[i] += Tc*V1[i] - tmp[i];
        // P2 += T*V2 - R@(K2a@Q2 + k2b)
        m3mul(tmp, t+65, Q2);
        #pragma unroll
        for (int i = 0; i < 9; ++i) tmp[i] += t[74+i];
        m3mul(tmp2, R, tmp);
        #pragma unroll
        for (int i = 0; i < 9; ++i) P2[i] += Tc*V2[i] - tmp2[i];
        // V1 -= R@M1
        m3mul(tmp, R, t+29);
        #pragma unroll
        for (int i = 0; i < 9; ++i) V1[i] -= tmp[i];
        // V2 -= R@(N@Q2 + n)
        m3mul(tmp, t+38, Q2);
        #pragma unroll
        for (int i = 0; i < 9; ++i) tmp[i] += t[47+i];
        m3mul(tmp2, R, tmp);
        #pragma unroll
        for (int i = 0; i < 9; ++i) V2[i] -= tmp2[i];
        // Q2 = A@Q2 + B
        m3mul(tmp, t+11, Q2);
        #pragma unroll
        for (int i = 0; i < 9; ++i) Q2[i] = tmp[i] + t[20+i];
        // p += v*T + R@z ; v += R@u
        float rz0 = R[0]*t[8] + R[1]*t[9] + R[2]*t[10];
        float rz1 = R[3]*t[8] + R[4]*t[9] + R[5]*t[10];
        float rz2 = R[6]*t[8] + R[7]*t[9] + R[8]*t[10];
        p[0] += v[0]*Tc + rz0; p[1] += v[1]*Tc + rz1; p[2] += v[2]*Tc + rz2;
        float ru0 = R[0]*t[5] + R[1]*t[6] + R[2]*t[7];
        float ru1 = R[3]*t[5] + R[4]*t[6] + R[5]*t[7];
        float ru2 = R[6]*t[5] + R[7]*t[6] + R[8]*t[7];
        v[0] += ru0; v[1] += ru1; v[2] += ru2;
        // q = q (x) E
        Q4 E = {t[0], t[1], t[2], t[3]};
        qq = qmul(Q4{q[0], q[1], q[2], q[3]}, E);
        q[0] = qq.x; q[1] = qq.y; q[2] = qq.z; q[3] = qq.w;
        kf += Tc;
    }

    // ---- epilogue for sequence m ----
    const float* bap0 = bias_a + (size_t)m * NS * 3;
    const float* bwp0 = bias_w + (size_t)m * NS * 3;
    float ba0x = bap0[0], ba0y = bap0[1], ba0z = bap0[2];
    float bw0x = bwp0[0], bw0y = bwp0[1], bw0z = bwp0[2];

    float alpha[3], beta[3];
    #pragma unroll
    for (int r = 0; r < 3; ++r) {
        alpha[r] = p[r] + P1[r*3+0]*ba0x + P1[r*3+1]*ba0y + P1[r*3+2]*ba0z
                        + P2[r*3+0]*bw0x + P2[r*3+1]*bw0y + P2[r*3+2]*bw0z;
        beta[r]  = v[r] + V1[r*3+0]*ba0x + V1[r*3+1]*ba0y + V1[r*3+2]*ba0z
                        + V2[r*3+0]*bw0x + V2[r*3+1]*bw0y + V2[r*3+2]*bw0z;
    }
    float dthx = 0.5f*(Q2[0]*bw0x + Q2[1]*bw0y + Q2[2]*bw0z);
    float dthy = 0.5f*(Q2[3]*bw0x + Q2[4]*bw0y + Q2[5]*bw0z);
    float dthz = 0.5f*(Q2[6]*bw0x + Q2[7]*bw0y + Q2[8]*bw0z);
    Q4 dq = {dthx, dthy, dthz, 1.0f};
    Q4 gamma = qmul(Q4{q[0], q[1], q[2], q[3]}, dq);

    float* g_gamma = ws;            // NM*4
    float* g_beta  = ws + 4*NM;     // NM*3
    float* g_alpha = ws + 7*NM;     // NM*3
    float* g_kf    = ws + 10*NM;    // NM
    g_gamma[m*4+0] = gamma.x; g_gamma[m*4+1] = gamma.y;
    g_gamma[m*4+2] = gamma.z; g_gamma[m*4+3] = gamma.w;
    g_beta[m*3+0] = beta[0];  g_beta[m*3+1] = beta[1];  g_beta[m*3+2] = beta[2];
    g_alpha[m*3+0] = alpha[0]; g_alpha[m*3+1] = alpha[1]; g_alpha[m*3+2] = alpha[2];
    g_kf[m] = kf;
}

// ------------------------------------------------------------------
// Phase 2: single block of 1024 threads. Quat scan + two float3 scans
// in LDS, then elementwise epilogue over K=1025.
// ------------------------------------------------------------------
__global__ __launch_bounds__(1024) void imu_phase2(
    const float* __restrict__ ws, const float* __restrict__ g,
    const float* __restrict__ init_rot, const float* __restrict__ init_pos,
    const float* __restrict__ init_vel, const float* __restrict__ gt_rot,
    const float* __restrict__ gt_pos, const float* __restrict__ gt_vel,
    float* __restrict__ out)
{
    __shared__ float4 srot[NK];
    __shared__ float  sbuf[NM][3];
    __shared__ float  svel[NK][3];
    __shared__ float  spos[NK][3];

    const int tid = threadIdx.x;

    const float* g_gamma = ws;
    const float* g_beta  = ws + 4*NM;
    const float* g_alpha = ws + 7*NM;
    const float* g_kf    = ws + 10*NM;

    Q4 qinit = {init_rot[0], init_rot[1], init_rot[2], init_rot[3]};

    srot[tid+1] = make_float4(g_gamma[tid*4+0], g_gamma[tid*4+1],
                              g_gamma[tid*4+2], g_gamma[tid*4+3]);
    __syncthreads();
    for (int off = 1; off < NM; off <<= 1) {
        float4 a4, b4 = srot[tid+1];
        bool act = (tid >= off);
        if (act) a4 = srot[tid+1-off];
        __syncthreads();
        if (act) {
            Q4 a = {a4.x, a4.y, a4.z, a4.w}, b = {b4.x, b4.y, b4.z, b4.w};
            Q4 c = qmul(a, b);
            srot[tid+1] = make_float4(c.x, c.y, c.z, c.w);
        }
        __syncthreads();
    }
    {
        float4 p4 = srot[tid+1];
        __syncthreads();
        Q4 p = {p4.x, p4.y, p4.z, p4.w};
        Q4 r = qmul(qinit, p);
        srot[tid+1] = make_float4(r.x, r.y, r.z, r.w);
        if (tid == 0) srot[0] = make_float4(qinit.x, qinit.y, qinit.z, qinit.w);
    }
    __syncthreads();

    const float gx = g[0], gy = g[1], gz = g[2];

    float4 r4 = srot[tid];
    Q4 rq = {r4.x, r4.y, r4.z, r4.w};
    float Rw[9]; q2m(rq, Rw);
    float kf = g_kf[tid];
    float bx = g_beta[tid*3+0], by = g_beta[tid*3+1], bz = g_beta[tid*3+2];
    float axm = g_alpha[tid*3+0], aym = g_alpha[tid*3+1], azm = g_alpha[tid*3+2];

    sbuf[tid][0] = -gx*kf + Rw[0]*bx + Rw[1]*by + Rw[2]*bz;
    sbuf[tid][1] = -gy*kf + Rw[3]*bx + Rw[4]*by + Rw[5]*bz;
    sbuf[tid][2] = -gz*kf + Rw[6]*bx + Rw[7]*by + Rw[8]*bz;
    __syncthreads();
    for (int off = 1; off < NM; off <<= 1) {
        float a0, a1, a2;
        float b0 = sbuf[tid][0], b1 = sbuf[tid][1], b2 = sbuf[tid][2];
        bool act = (tid >= off);
        if (act) { a0 = sbuf[tid-off][0]; a1 = sbuf[tid-off][1]; a2 = sbuf[tid-off][2]; }
        __syncthreads();
        if (act) { sbuf[tid][0] = a0+b0; sbuf[tid][1] = a1+b1; sbuf[tid][2] = a2+b2; }
        __syncthreads();
    }
    if (tid == 0) { svel[0][0] = init_vel[0]; svel[0][1] = init_vel[1]; svel[0][2] = init_vel[2]; }
    svel[tid+1][0] = init_vel[0] + sbuf[tid][0];
    svel[tid+1][1] = init_vel[1] + sbuf[tid][1];
    svel[tid+1][2] = init_vel[2] + sbuf[tid][2];
    __syncthreads();

    float vmx = svel[tid][0], vmy = svel[tid][1], vmz = svel[tid][2];
    __syncthreads();
    sbuf[tid][0] = vmx*kf - 0.5f*gx*kf*kf + Rw[0]*axm + Rw[1]*aym + Rw[2]*azm;
    sbuf[tid][1] = vmy*kf - 0.5f*gy*kf*kf + Rw[3]*axm + Rw[4]*aym + Rw[5]*azm;
    sbuf[tid][2] = vmz*kf - 0.5f*gz*kf*kf + Rw[6]*axm + Rw[7]*aym + Rw[8]*azm;
    __syncthreads();
    for (int off = 1; off < NM; off <<= 1) {
        float a0, a1, a2;
        float b0 = sbuf[tid][0], b1 = sbuf[tid][1], b2 = sbuf[tid][2];
        bool act = (tid >= off);
        if (act) { a0 = sbuf[tid-off][0]; a1 = sbuf[tid-off][1]; a2 = sbuf[tid-off][2]; }
        __syncthreads();
        if (act) { sbuf[tid][0] = a0+b0; sbuf[tid][1] = a1+b1; sbuf[tid][2] = a2+b2; }
        __syncthreads();
    }
    if (tid == 0) { spos[0][0] = init_pos[0]; spos[0][1] = init_pos[1]; spos[0][2] = init_pos[2]; }
    spos[tid+1][0] = init_pos[0] + sbuf[tid][0];
    spos[tid+1][1] = init_pos[1] + sbuf[tid][1];
    spos[tid+1][2] = init_pos[2] + sbuf[tid][2];
    __syncthreads();

    for (int k = tid; k < NK; k += 1024) {
        float4 rr = srot[k];
        Q4 rk = {rr.x, rr.y, rr.z, rr.w};
        Q4 gc = {-gt_rot[k*4+0], -gt_rot[k*4+1], -gt_rot[k*4+2], gt_rot[k*4+3]};
        Q4 e = qmul(gc, rk);
        float n2 = e.x*e.x + e.y*e.y + e.z*e.z;
        float n = sqrtf(n2);
        float theta = 2.f*atan2f(n, e.w);
        float scale;
        if (n < 1e-6f) {
            float wd = (fabsf(e.w) < 1e-6f) ? 1.f : e.w;
            scale = 2.f/wd;
        } else {
            scale = theta/n;
        }
        out[k*3+0] = e.x*scale;
        out[k*3+1] = e.y*scale;
        out[k*3+2] = e.z*scale;

        float d0 = gt_pos[k*3+0] - spos[k][0];
        float d1 = gt_pos[k*3+1] - spos[k][1];
        float d2 = gt_pos[k*3+2] - spos[k][2];
        out[(NK+k)*3+0] = d0*d0;
        out[(NK+k)*3+1] = d1*d1;
        out[(NK+k)*3+2] = d2*d2;

        float e0 = gt_vel[k*3+0] - svel[k][0];
        float e1 = gt_vel[k*3+1] - svel[k][1];
        float e2 = gt_vel[k*3+2] - svel[k][2];
        out[(2*NK+k)*3+0] = e0*e0;
        out[(2*NK+k)*3+1] = e1*e1;
        out[(2*NK+k)*3+2] = e2*e2;
    }
}

extern "C" void kernel_launch(void* const* d_in, const int* in_sizes, int n_in,
                              void* d_out, int out_size, void* d_ws, size_t ws_size,
                              hipStream_t stream) {
    const float* acc      = (const float*)d_in[0];
    const float* gyro     = (const float*)d_in[1];
    const float* dt       = (const float*)d_in[2];
    const float* bias_a   = (const float*)d_in[3];
    const float* bias_w   = (const float*)d_in[4];
    const float* g        = (const float*)d_in[5];
    const float* init_rot = (const float*)d_in[6];
    const float* init_pos = (const float*)d_in[7];
    const float* init_vel = (const float*)d_in[8];
    const float* gt_rot   = (const float*)d_in[9];
    const float* gt_pos   = (const float*)d_in[10];
    const float* gt_vel   = (const float*)d_in[11];
    float* ws  = (float*)d_ws;
    float* out = (float*)d_out;

    imu_phase1<<<NM/SEQ_PER_BLK, 64, 0, stream>>>(acc, gyro, dt, bias_a, bias_w, ws);
    imu_phase2<<<1, 1024, 0, stream>>>(ws, g, init_rot, init_pos, init_vel,
                                       gt_rot, gt_pos, gt_vel, out);
}